// Round 3
// baseline (427.709 us; speedup 1.0000x reference)
//
#include <hip/hip_runtime.h>
#include <hip/hip_bf16.h>
#include <math.h>
#include <stdint.h>

typedef __bf16 bf16;
typedef __bf16 bf16x8 __attribute__((ext_vector_type(8)));
typedef float f32x4 __attribute__((ext_vector_type(4)));

#define MFMA16(a, b, c) __builtin_amdgcn_mfma_f32_16x16x32_bf16((a), (b), (c), 0, 0, 0)

constexpr int EMB = 1024;
constexpr int SEQ = 2048;
constexpr int BATCH = 2;
constexpr int NTOK = BATCH * SEQ;   // 4096
constexpr int FFN = 4 * EMB;        // 4096
constexpr int HEADS = 16;
constexpr int HDIM = 64;

// async 16B global -> LDS (wave-uniform base + lane*16 destination)
__device__ __forceinline__ void gload16(const void* g, void* l) {
    __builtin_amdgcn_global_load_lds(
        (const __attribute__((address_space(1))) void*)g,
        (__attribute__((address_space(3))) void*)l,
        16, 0, 0);
}

// ---------------- LayerNorm: fp32 in -> bf16 out --------------------------
__global__ __launch_bounds__(256) void ln_kernel(const float* __restrict__ x,
                                                 const float* __restrict__ g,
                                                 const float* __restrict__ b,
                                                 bf16* __restrict__ out) {
    int row = blockIdx.x;
    int t = threadIdx.x;
    float4 v = reinterpret_cast<const float4*>(x + (size_t)row * EMB)[t];
    float s = v.x + v.y + v.z + v.w;
    float s2 = v.x * v.x + v.y * v.y + v.z * v.z + v.w * v.w;
#pragma unroll
    for (int o = 1; o < 64; o <<= 1) {
        s += __shfl_xor(s, o);
        s2 += __shfl_xor(s2, o);
    }
    __shared__ float ps[4], ps2[4];
    int w = t >> 6;
    if ((t & 63) == 0) { ps[w] = s; ps2[w] = s2; }
    __syncthreads();
    s = ps[0] + ps[1] + ps[2] + ps[3];
    s2 = ps2[0] + ps2[1] + ps2[2] + ps2[3];
    float mean = s * (1.f / EMB);
    float var = s2 * (1.f / EMB) - mean * mean;
    float rstd = rsqrtf(var + 1e-5f);
    float4 gv = reinterpret_cast<const float4*>(g)[t];
    float4 bv = reinterpret_cast<const float4*>(b)[t];
    bf16* op = out + (size_t)row * EMB + t * 4;
    op[0] = (bf16)(gv.x * (v.x - mean) * rstd + bv.x);
    op[1] = (bf16)(gv.y * (v.y - mean) * rstd + bv.y);
    op[2] = (bf16)(gv.z * (v.z - mean) * rstd + bv.z);
    op[3] = (bf16)(gv.w * (v.w - mean) * rstd + bv.w);
}

// ---------------- transpose + cast: W[K][N] f32 -> Wt[N][K] bf16 ----------
__global__ __launch_bounds__(256) void transpose_cast(const float* __restrict__ W,
                                                      bf16* __restrict__ Wt,
                                                      int K, int N) {
    __shared__ float t[32][33];
    int n0 = blockIdx.x * 32, k0 = blockIdx.y * 32;
    int tx = threadIdx.x, ty = threadIdx.y;  // 32 x 8
#pragma unroll
    for (int i = 0; i < 4; i++)
        t[ty + 8 * i][tx] = W[(size_t)(k0 + ty + 8 * i) * N + n0 + tx];
    __syncthreads();
#pragma unroll
    for (int i = 0; i < 4; i++)
        Wt[(size_t)(n0 + ty + 8 * i) * K + k0 + tx] = (bf16)t[tx][ty + 8 * i];
}

// ---------------- V transpose: [B,H,S,64] -> [B,H,64,S] bf16 --------------
__global__ __launch_bounds__(256) void vtrans(const bf16* __restrict__ v,
                                              bf16* __restrict__ vt) {
    int bh = blockIdx.y;
    int s0 = blockIdx.x * 64;
    const bf16* src = v + (size_t)bh * SEQ * HDIM + (size_t)s0 * HDIM;
    bf16* dst = vt + (size_t)bh * HDIM * SEQ + s0;
    __shared__ bf16 tile[64][72];
    int t = threadIdx.x;
    int s = t >> 2, d0 = (t & 3) * 16;
    bf16x8 a = *reinterpret_cast<const bf16x8*>(src + s * HDIM + d0);
    bf16x8 b = *reinterpret_cast<const bf16x8*>(src + s * HDIM + d0 + 8);
#pragma unroll
    for (int e = 0; e < 8; e++) {
        tile[d0 + e][s] = a[e];
        tile[d0 + 8 + e][s] = b[e];
    }
    __syncthreads();
    int d = t >> 2, c0 = (t & 3) * 16;
    bf16x8 o0 = *reinterpret_cast<const bf16x8*>(&tile[d][c0]);
    bf16x8 o1 = *reinterpret_cast<const bf16x8*>(&tile[d][c0 + 8]);
    *reinterpret_cast<bf16x8*>(dst + (size_t)d * SEQ + c0) = o0;
    *reinterpret_cast<bf16x8*>(dst + (size_t)d * SEQ + c0 + 8) = o1;
}

// ---------------- LDS-staged GEMM (m97 structure) -------------------------
// C = epi(A[M][K] @ Bt[N][K]^T), BK=32, 4 waves in 2x2, per-wave (BM/2)x(BN/2)
// MODE 0: fused QKV scatter -> bf16 q/k/v [B,H,S,64] (q scaled 1/8)
// MODE 1: out f32 = resid + acc + bias
// MODE 2: out bf16 = gelu(acc + bias)
template <int BM, int BN, int MODE>
__global__ __launch_bounds__(256) void gemm_lds(const bf16* __restrict__ A,
                                                const bf16* __restrict__ Bt,
                                                int M, int N, int K,
                                                float* __restrict__ outF,
                                                bf16* __restrict__ outB,
                                                const float* __restrict__ bias,
                                                const float* __restrict__ resid) {
    constexpr int MR = BM / 32;              // M frags per wave
    constexpr int NR = BN / 32;              // N frags per wave
    constexpr int ACH = (BM * 64) / 4096;    // 16B chunks/thread for A tile
    constexpr int BCH = (BN * 64) / 4096;
    __shared__ bf16 sA[BM * 32];
    __shared__ bf16 sB[BN * 32];
    int t = threadIdx.x;
    int wave = t >> 6, lane = t & 63;
    int wr = wave >> 1, wc = wave & 1;
    int lr = lane & 15, lg = lane >> 4;
    int row0 = blockIdx.x * BM;
    int col0 = blockIdx.y * BN;

    // staging source pointers (advance 64B per K-step)
    const char* aS[ACH];
    const char* bS[BCH];
#pragma unroll
    for (int c = 0; c < ACH; c++) {
        int o = (t + c * 256) * 16;
        aS[c] = (const char*)A + (size_t)(row0 + (o >> 6)) * K * 2 + (o & 63);
    }
#pragma unroll
    for (int c = 0; c < BCH; c++) {
        int o = (t + c * 256) * 16;
        bS[c] = (const char*)Bt + (size_t)(col0 + (o >> 6)) * K * 2 + (o & 63);
    }

    f32x4 acc[MR][NR];
#pragma unroll
    for (int m = 0; m < MR; m++)
#pragma unroll
        for (int n = 0; n < NR; n++) acc[m][n] = f32x4{0.f, 0.f, 0.f, 0.f};

    for (int k0 = 0; k0 < K; k0 += 32) {
        __syncthreads();
#pragma unroll
        for (int c = 0; c < ACH; c++)
            gload16(aS[c], (char*)sA + (t + c * 256) * 16);
#pragma unroll
        for (int c = 0; c < BCH; c++)
            gload16(bS[c], (char*)sB + (t + c * 256) * 16);
#pragma unroll
        for (int c = 0; c < ACH; c++) aS[c] += 64;
#pragma unroll
        for (int c = 0; c < BCH; c++) bS[c] += 64;
        __syncthreads();

        bf16x8 a[MR], b[NR];
#pragma unroll
        for (int m = 0; m < MR; m++)
            a[m] = *reinterpret_cast<const bf16x8*>(
                sA + (wr * (BM / 2) + m * 16 + lr) * 32 + 8 * lg);
#pragma unroll
        for (int n = 0; n < NR; n++)
            b[n] = *reinterpret_cast<const bf16x8*>(
                sB + (wc * (BN / 2) + n * 16 + lr) * 32 + 8 * lg);
#pragma unroll
        for (int m = 0; m < MR; m++)
#pragma unroll
            for (int n = 0; n < NR; n++)
                acc[m][n] = MFMA16(a[m], b[n], acc[m][n]);
    }

#pragma unroll
    for (int m = 0; m < MR; m++) {
#pragma unroll
        for (int r = 0; r < 4; r++) {
            int row = row0 + wr * (BM / 2) + m * 16 + 4 * lg + r;
#pragma unroll
            for (int n = 0; n < NR; n++) {
                int col = col0 + wc * (BN / 2) + n * 16 + lr;
                float v = acc[m][n][r];
                if (MODE == 0) {
                    int b_ = row >> 11, s_ = row & 2047;
                    int which = col >> 10, rem = col & 1023;
                    int h_ = rem >> 6, d_ = rem & 63;
                    float sc = (which == 0) ? 0.125f : 1.0f;
                    outB[(size_t)which * (NTOK * EMB) +
                         (((size_t)(b_ * HEADS + h_) * SEQ + s_) << 6) + d_] =
                        (bf16)(v * sc);
                } else if (MODE == 1) {
                    size_t idx = (size_t)row * N + col;
                    outF[idx] = resid[idx] + v + bias[col];
                } else {
                    float u = v + bias[col];
                    float gl = 0.5f * u *
                               (1.f + tanhf(0.7978845608028654f *
                                            (u + 0.044715f * u * u * u)));
                    outB[(size_t)row * N + col] = (bf16)gl;
                }
            }
        }
    }
}

// ---------------- causal flash attention (barrier-free waves) -------------
// q,k: [B,H,S,64] bf16 (q pre-scaled by 1/8); vt: [B,H,64,S] bf16
// ctx out: [B,S,H*64] bf16.  2 waves/block, each wave owns 32 q-rows.
__global__ __launch_bounds__(128) void attn_kernel(const bf16* __restrict__ q,
                                                   const bf16* __restrict__ k,
                                                   const bf16* __restrict__ vt,
                                                   bf16* __restrict__ ctx) {
    int bh = blockIdx.y;
    const bf16* qh = q + (size_t)bh * SEQ * HDIM;
    const bf16* kh = k + (size_t)bh * SEQ * HDIM;
    const bf16* vh = vt + (size_t)bh * HDIM * SEQ;  // [64][2048]
    int wave = threadIdx.x >> 6, lane = threadIdx.x & 63;
    int lr = lane & 15, lg = lane >> 4;
    // heavy (late-q) blocks first
    int wq0 = (gridDim.x - 1 - blockIdx.x) * 64 + wave * 32;

    __shared__ bf16 plds[2][32][72];

    bf16x8 qf[2][2];
#pragma unroll
    for (int m = 0; m < 2; m++)
#pragma unroll
        for (int j = 0; j < 2; j++)
            qf[m][j] = *reinterpret_cast<const bf16x8*>(
                qh + (size_t)(wq0 + m * 16 + lr) * HDIM + j * 32 + 8 * lg);

    f32x4 o[2][4];
#pragma unroll
    for (int m = 0; m < 2; m++)
#pragma unroll
        for (int n = 0; n < 4; n++) o[m][n] = f32x4{0.f, 0.f, 0.f, 0.f};
    float mrow[2][4], lrow[2][4];
#pragma unroll
    for (int m = 0; m < 2; m++)
#pragma unroll
        for (int r = 0; r < 4; r++) { mrow[m][r] = -1e30f; lrow[m][r] = 0.f; }

    int kend = wq0 + 32;
    for (int c0 = 0; c0 < kend; c0 += 64) {
        // ---- QK^T (K frags direct from global, contiguous 16B) ----
        f32x4 sc[2][4];
#pragma unroll
        for (int n = 0; n < 4; n++) {
            const bf16* kp = kh + (size_t)(c0 + n * 16 + lr) * HDIM + 8 * lg;
            bf16x8 kf0 = *reinterpret_cast<const bf16x8*>(kp);
            bf16x8 kf1 = *reinterpret_cast<const bf16x8*>(kp + 32);
#pragma unroll
            for (int m = 0; m < 2; m++) {
                f32x4 tAcc = f32x4{0.f, 0.f, 0.f, 0.f};
                tAcc = MFMA16(qf[m][0], kf0, tAcc);
                tAcc = MFMA16(qf[m][1], kf1, tAcc);
                sc[m][n] = tAcc;
            }
        }
        if (c0 + 63 > wq0) {  // chunk touches the diagonal: causal mask
#pragma unroll
            for (int m = 0; m < 2; m++)
#pragma unroll
                for (int n = 0; n < 4; n++)
#pragma unroll
                    for (int r = 0; r < 4; r++)
                        if (c0 + n * 16 + lr > wq0 + m * 16 + 4 * lg + r)
                            sc[m][n][r] = -1e30f;
        }

        // ---- online softmax (16-lane groups hold a row) ----
#pragma unroll
        for (int m = 0; m < 2; m++) {
#pragma unroll
            for (int r = 0; r < 4; r++) {
                float mp = fmaxf(fmaxf(sc[m][0][r], sc[m][1][r]),
                                 fmaxf(sc[m][2][r], sc[m][3][r]));
#pragma unroll
                for (int off = 1; off < 16; off <<= 1)
                    mp = fmaxf(mp, __shfl_xor(mp, off));
                float mn = fmaxf(mrow[m][r], mp);
                float sclr = __expf(mrow[m][r] - mn);
                mrow[m][r] = mn;
                float ps = 0.f;
#pragma unroll
                for (int n = 0; n < 4; n++) {
                    float p = __expf(sc[m][n][r] - mn);
                    ps += p;
                    plds[wave][m * 16 + 4 * lg + r][n * 16 + lr] = (bf16)p;
                }
#pragma unroll
                for (int off = 1; off < 16; off <<= 1) ps += __shfl_xor(ps, off);
                lrow[m][r] = lrow[m][r] * sclr + ps;
#pragma unroll
                for (int n = 0; n < 4; n++) o[m][n][r] *= sclr;
            }
        }

        // ---- PV (V^T frags direct from global, contiguous 16B) ----
#pragma unroll
        for (int ks = 0; ks < 2; ks++) {
            bf16x8 pa[2];
#pragma unroll
            for (int m = 0; m < 2; m++)
                pa[m] = *reinterpret_cast<const bf16x8*>(
                    &plds[wave][m * 16 + lr][ks * 32 + 8 * lg]);
#pragma unroll
            for (int n = 0; n < 4; n++) {
                bf16x8 bv = *reinterpret_cast<const bf16x8*>(
                    vh + (size_t)(n * 16 + lr) * SEQ + c0 + ks * 32 + 8 * lg);
#pragma unroll
                for (int m = 0; m < 2; m++) o[m][n] = MFMA16(pa[m], bv, o[m][n]);
            }
        }
    }

    int b_ = bh >> 4, h_ = bh & 15;
#pragma unroll
    for (int m = 0; m < 2; m++) {
#pragma unroll
        for (int r = 0; r < 4; r++) {
            int srow = wq0 + m * 16 + 4 * lg + r;
            float inv = 1.f / lrow[m][r];
            size_t base = ((size_t)b_ * SEQ + srow) * EMB + h_ * HDIM;
#pragma unroll
            for (int n = 0; n < 4; n++)
                ctx[base + n * 16 + lr] = (bf16)(o[m][n][r] * inv);
        }
    }
}

// ---------------- launch ---------------------------------------------------
extern "C" void kernel_launch(void* const* d_in, const int* in_sizes, int n_in,
                              void* d_out, int out_size, void* d_ws, size_t ws_size,
                              hipStream_t stream) {
    const float* x  = (const float*)d_in[0];
    const float* Wq = (const float*)d_in[1];
    const float* Wk = (const float*)d_in[2];
    const float* Wv = (const float*)d_in[3];
    const float* Wo = (const float*)d_in[4];
    const float* bo = (const float*)d_in[5];
    const float* W1 = (const float*)d_in[6];
    const float* b1 = (const float*)d_in[7];
    const float* W2 = (const float*)d_in[8];
    const float* b2 = (const float*)d_in[9];
    const float* g1 = (const float*)d_in[10];
    const float* s1 = (const float*)d_in[11];
    const float* g2 = (const float*)d_in[12];
    const float* s2 = (const float*)d_in[13];

    const size_t MB = 1ull << 20;
    char* w = (char*)d_ws;
    bf16* Wqkvt = (bf16*)(w + 0 * MB);            // [3072][1024] contiguous
    bf16* Wqt = Wqkvt;
    bf16* Wkt = (bf16*)(w + 2 * MB);
    bf16* Wvt = (bf16*)(w + 4 * MB);
    bf16* Wot = (bf16*)(w + 6 * MB);
    bf16* W1t = (bf16*)(w + 8 * MB);
    bf16* W2t = (bf16*)(w + 16 * MB);
    bf16* hbuf = (bf16*)(w + 24 * MB);            // h1 / h2 (reused)
    bf16* vtb  = (bf16*)(w + 24 * MB);            // aliases hbuf: used between QKV and LN2
    bf16* qkvb = (bf16*)(w + 32 * MB);            // q @32, k @40, v @48 MB
    bf16* qb   = (bf16*)(w + 32 * MB);
    bf16* kb   = (bf16*)(w + 40 * MB);
    bf16* vb   = (bf16*)(w + 48 * MB);
    bf16* ctxb = (bf16*)(w + 56 * MB);
    bf16* midb = (bf16*)(w + 32 * MB);            // reuses qkv after attn
    float* x1  = (float*)(w + 64 * MB);

    dim3 tb(32, 8);
    // weight transposes (fp32 -> bf16 [N][K]); Wq/Wk/Wv contiguous
    transpose_cast<<<dim3(EMB / 32, EMB / 32), tb, 0, stream>>>(Wq, Wqt, EMB, EMB);
    transpose_cast<<<dim3(EMB / 32, EMB / 32), tb, 0, stream>>>(Wk, Wkt, EMB, EMB);
    transpose_cast<<<dim3(EMB / 32, EMB / 32), tb, 0, stream>>>(Wv, Wvt, EMB, EMB);
    transpose_cast<<<dim3(EMB / 32, EMB / 32), tb, 0, stream>>>(Wo, Wot, EMB, EMB);
    transpose_cast<<<dim3(FFN / 32, EMB / 32), tb, 0, stream>>>(W1, W1t, EMB, FFN);
    transpose_cast<<<dim3(EMB / 32, FFN / 32), tb, 0, stream>>>(W2, W2t, FFN, EMB);

    // LN1
    ln_kernel<<<NTOK, 256, 0, stream>>>(x, g1, s1, hbuf);

    // fused QKV projection: [4096,1024] @ [3072,1024]^T
    gemm_lds<128, 128, 0><<<dim3(NTOK / 128, 3072 / 128), 256, 0, stream>>>(
        hbuf, Wqkvt, NTOK, 3072, EMB, nullptr, qkvb, nullptr, nullptr);

    // V -> V^T  [B,H,64,S]  (hbuf region is free until LN2)
    vtrans<<<dim3(SEQ / 64, BATCH * HEADS), 256, 0, stream>>>(vb, vtb);

    // attention (barrier-free; 2 waves/block, 32 q-rows/wave)
    attn_kernel<<<dim3(SEQ / 64, BATCH * HEADS), 128, 0, stream>>>(qb, kb, vtb, ctxb);

    // output projection + residual -> x1 (f32)
    gemm_lds<128, 64, 1><<<dim3(NTOK / 128, EMB / 64), 256, 0, stream>>>(
        ctxb, Wot, NTOK, EMB, EMB, x1, nullptr, bo, x);

    // LN2
    ln_kernel<<<NTOK, 256, 0, stream>>>(x1, g2, s2, hbuf);

    // FFN1 + gelu -> bf16 mid
    gemm_lds<128, 128, 2><<<dim3(NTOK / 128, FFN / 128), 256, 0, stream>>>(
        hbuf, W1t, NTOK, FFN, EMB, nullptr, midb, b1, nullptr);

    // FFN2 + bias + residual -> d_out (f32)
    gemm_lds<128, 64, 1><<<dim3(NTOK / 128, EMB / 64), 256, 0, stream>>>(
        midb, W2t, NTOK, EMB, FFN, (float*)d_out, nullptr, b2, x1);
}

// Round 4
// 414.432 us; speedup vs baseline: 1.0320x; 1.0320x over previous
//
#include <hip/hip_runtime.h>
#include <hip/hip_bf16.h>
#include <math.h>
#include <stdint.h>

typedef __bf16 bf16;
typedef __bf16 bf16x8 __attribute__((ext_vector_type(8)));
typedef float f32x4 __attribute__((ext_vector_type(4)));

#define MFMA16(a, b, c) __builtin_amdgcn_mfma_f32_16x16x32_bf16((a), (b), (c), 0, 0, 0)

constexpr int EMB = 1024;
constexpr int SEQ = 2048;
constexpr int BATCH = 2;
constexpr int NTOK = BATCH * SEQ;   // 4096
constexpr int FFN = 4 * EMB;        // 4096
constexpr int HEADS = 16;
constexpr int HDIM = 64;

// async 16B global -> LDS (wave-uniform base + lane*16 destination)
__device__ __forceinline__ void gload16(const void* g, void* l) {
    __builtin_amdgcn_global_load_lds(
        (const __attribute__((address_space(1))) void*)g,
        (__attribute__((address_space(3))) void*)l,
        16, 0, 0);
}

// ---------------- LayerNorm: fp32 in -> bf16 out --------------------------
__global__ __launch_bounds__(256) void ln_kernel(const float* __restrict__ x,
                                                 const float* __restrict__ g,
                                                 const float* __restrict__ b,
                                                 bf16* __restrict__ out) {
    int row = blockIdx.x;
    int t = threadIdx.x;
    float4 v = reinterpret_cast<const float4*>(x + (size_t)row * EMB)[t];
    float s = v.x + v.y + v.z + v.w;
    float s2 = v.x * v.x + v.y * v.y + v.z * v.z + v.w * v.w;
#pragma unroll
    for (int o = 1; o < 64; o <<= 1) {
        s += __shfl_xor(s, o);
        s2 += __shfl_xor(s2, o);
    }
    __shared__ float ps[4], ps2[4];
    int w = t >> 6;
    if ((t & 63) == 0) { ps[w] = s; ps2[w] = s2; }
    __syncthreads();
    s = ps[0] + ps[1] + ps[2] + ps[3];
    s2 = ps2[0] + ps2[1] + ps2[2] + ps2[3];
    float mean = s * (1.f / EMB);
    float var = s2 * (1.f / EMB) - mean * mean;
    float rstd = rsqrtf(var + 1e-5f);
    float4 gv = reinterpret_cast<const float4*>(g)[t];
    float4 bv = reinterpret_cast<const float4*>(b)[t];
    bf16* op = out + (size_t)row * EMB + t * 4;
    op[0] = (bf16)(gv.x * (v.x - mean) * rstd + bv.x);
    op[1] = (bf16)(gv.y * (v.y - mean) * rstd + bv.y);
    op[2] = (bf16)(gv.z * (v.z - mean) * rstd + bv.z);
    op[3] = (bf16)(gv.w * (v.w - mean) * rstd + bv.w);
}

// ---------------- transpose + cast: W[K][N] f32 -> Wt[N][K] bf16 ----------
__global__ __launch_bounds__(256) void transpose_cast(const float* __restrict__ W,
                                                      bf16* __restrict__ Wt,
                                                      int K, int N) {
    __shared__ float t[32][33];
    int n0 = blockIdx.x * 32, k0 = blockIdx.y * 32;
    int tx = threadIdx.x, ty = threadIdx.y;  // 32 x 8
#pragma unroll
    for (int i = 0; i < 4; i++)
        t[ty + 8 * i][tx] = W[(size_t)(k0 + ty + 8 * i) * N + n0 + tx];
    __syncthreads();
#pragma unroll
    for (int i = 0; i < 4; i++)
        Wt[(size_t)(n0 + ty + 8 * i) * K + k0 + tx] = (bf16)t[tx][ty + 8 * i];
}

// ---------------- V transpose: [B,H,S,64] -> [B,H,64,S] bf16 --------------
__global__ __launch_bounds__(256) void vtrans(const bf16* __restrict__ v,
                                              bf16* __restrict__ vt) {
    int bh = blockIdx.y;
    int s0 = blockIdx.x * 64;
    const bf16* src = v + (size_t)bh * SEQ * HDIM + (size_t)s0 * HDIM;
    bf16* dst = vt + (size_t)bh * HDIM * SEQ + s0;
    __shared__ bf16 tile[64][72];
    int t = threadIdx.x;
    int s = t >> 2, d0 = (t & 3) * 16;
    bf16x8 a = *reinterpret_cast<const bf16x8*>(src + s * HDIM + d0);
    bf16x8 b = *reinterpret_cast<const bf16x8*>(src + s * HDIM + d0 + 8);
#pragma unroll
    for (int e = 0; e < 8; e++) {
        tile[d0 + e][s] = a[e];
        tile[d0 + 8 + e][s] = b[e];
    }
    __syncthreads();
    int d = t >> 2, c0 = (t & 3) * 16;
    bf16x8 o0 = *reinterpret_cast<const bf16x8*>(&tile[d][c0]);
    bf16x8 o1 = *reinterpret_cast<const bf16x8*>(&tile[d][c0 + 8]);
    *reinterpret_cast<bf16x8*>(dst + (size_t)d * SEQ + c0) = o0;
    *reinterpret_cast<bf16x8*>(dst + (size_t)d * SEQ + c0 + 8) = o1;
}

// ---------------- LDS-staged GEMM (m97 structure) -------------------------
// C = epi(A[M][K] @ Bt[N][K]^T), BK=32, 4 waves in 2x2, per-wave (BM/2)x(BN/2)
// MODE 0: fused QKV scatter -> bf16 q/k/v [B,H,S,64] (q scaled 1/8)
// MODE 1: out f32 = resid + acc + bias
// MODE 2: out bf16 = gelu(acc + bias)
template <int BM, int BN, int MODE>
__global__ __launch_bounds__(256) void gemm_lds(const bf16* __restrict__ A,
                                                const bf16* __restrict__ Bt,
                                                int M, int N, int K,
                                                float* __restrict__ outF,
                                                bf16* __restrict__ outB,
                                                const float* __restrict__ bias,
                                                const float* __restrict__ resid) {
    constexpr int MR = BM / 32;              // M frags per wave
    constexpr int NR = BN / 32;              // N frags per wave
    constexpr int ACH = (BM * 64) / 4096;    // 16B chunks/thread for A tile
    constexpr int BCH = (BN * 64) / 4096;
    __shared__ bf16 sA[BM * 32];
    __shared__ bf16 sB[BN * 32];
    int t = threadIdx.x;
    int wave = t >> 6, lane = t & 63;
    int wr = wave >> 1, wc = wave & 1;
    int lr = lane & 15, lg = lane >> 4;
    int row0 = blockIdx.x * BM;
    int col0 = blockIdx.y * BN;

    // staging source pointers (advance 64B per K-step)
    const char* aS[ACH];
    const char* bS[BCH];
#pragma unroll
    for (int c = 0; c < ACH; c++) {
        int o = (t + c * 256) * 16;
        aS[c] = (const char*)A + (size_t)(row0 + (o >> 6)) * K * 2 + (o & 63);
    }
#pragma unroll
    for (int c = 0; c < BCH; c++) {
        int o = (t + c * 256) * 16;
        bS[c] = (const char*)Bt + (size_t)(col0 + (o >> 6)) * K * 2 + (o & 63);
    }

    f32x4 acc[MR][NR];
#pragma unroll
    for (int m = 0; m < MR; m++)
#pragma unroll
        for (int n = 0; n < NR; n++) acc[m][n] = f32x4{0.f, 0.f, 0.f, 0.f};

    for (int k0 = 0; k0 < K; k0 += 32) {
        __syncthreads();
#pragma unroll
        for (int c = 0; c < ACH; c++)
            gload16(aS[c], (char*)sA + (t + c * 256) * 16);
#pragma unroll
        for (int c = 0; c < BCH; c++)
            gload16(bS[c], (char*)sB + (t + c * 256) * 16);
#pragma unroll
        for (int c = 0; c < ACH; c++) aS[c] += 64;
#pragma unroll
        for (int c = 0; c < BCH; c++) bS[c] += 64;
        __syncthreads();

        bf16x8 a[MR], b[NR];
#pragma unroll
        for (int m = 0; m < MR; m++)
            a[m] = *reinterpret_cast<const bf16x8*>(
                sA + (wr * (BM / 2) + m * 16 + lr) * 32 + 8 * lg);
#pragma unroll
        for (int n = 0; n < NR; n++)
            b[n] = *reinterpret_cast<const bf16x8*>(
                sB + (wc * (BN / 2) + n * 16 + lr) * 32 + 8 * lg);
#pragma unroll
        for (int m = 0; m < MR; m++)
#pragma unroll
            for (int n = 0; n < NR; n++)
                acc[m][n] = MFMA16(a[m], b[n], acc[m][n]);
    }

#pragma unroll
    for (int m = 0; m < MR; m++) {
#pragma unroll
        for (int r = 0; r < 4; r++) {
            int row = row0 + wr * (BM / 2) + m * 16 + 4 * lg + r;
#pragma unroll
            for (int n = 0; n < NR; n++) {
                int col = col0 + wc * (BN / 2) + n * 16 + lr;
                float v = acc[m][n][r];
                if (MODE == 0) {
                    int b_ = row >> 11, s_ = row & 2047;
                    int which = col >> 10, rem = col & 1023;
                    int h_ = rem >> 6, d_ = rem & 63;
                    float sc = (which == 0) ? 0.125f : 1.0f;
                    outB[(size_t)which * (NTOK * EMB) +
                         (((size_t)(b_ * HEADS + h_) * SEQ + s_) << 6) + d_] =
                        (bf16)(v * sc);
                } else if (MODE == 1) {
                    size_t idx = (size_t)row * N + col;
                    outF[idx] = resid[idx] + v + bias[col];
                } else {
                    float u = v + bias[col];
                    float gl = 0.5f * u *
                               (1.f + tanhf(0.7978845608028654f *
                                            (u + 0.044715f * u * u * u)));
                    outB[(size_t)row * N + col] = (bf16)gl;
                }
            }
        }
    }
}

// ---------------- causal flash attention ----------------------------------
// Barrier-free waves + high occupancy: 4 waves/block, 16 q-rows/wave.
// q,k: [B,H,S,64] bf16 (q pre-scaled by 1/8); vt: [B,H,64,S] bf16
// ctx out: [B,S,H*64] bf16.
// Grid: 1024 blocks, XCD-bijective swizzle so each XCD owns 4 whole heads
// (K+V = 2 MB per XCD -> L2-resident), late-q blocks first within a head.
__global__ __launch_bounds__(256) void attn_kernel(const bf16* __restrict__ q,
                                                   const bf16* __restrict__ k,
                                                   const bf16* __restrict__ vt,
                                                   bf16* __restrict__ ctx) {
    int wg = blockIdx.x;
    int wgid = (wg & 7) * 128 + (wg >> 3);   // bijective: 1024 = 8 XCD * 128
    int bh = wgid >> 5;                      // 4 heads per XCD, contiguous
    int q0 = (31 - (wgid & 31)) * 64;        // late (heavy) q-blocks first
    const bf16* qh = q + (size_t)bh * SEQ * HDIM;
    const bf16* kh = k + (size_t)bh * SEQ * HDIM;
    const bf16* vh = vt + (size_t)bh * HDIM * SEQ;  // [64][2048]
    int wave = threadIdx.x >> 6, lane = threadIdx.x & 63;
    int lr = lane & 15, lg = lane >> 4;
    int qrow = q0 + wave * 16;

    __shared__ bf16 plds[4][16][72];  // per-wave P, padded stride

    bf16x8 qf0 = *reinterpret_cast<const bf16x8*>(qh + (size_t)(qrow + lr) * HDIM + 8 * lg);
    bf16x8 qf1 = *reinterpret_cast<const bf16x8*>(qh + (size_t)(qrow + lr) * HDIM + 32 + 8 * lg);

    f32x4 o[4];
#pragma unroll
    for (int n = 0; n < 4; n++) o[n] = f32x4{0.f, 0.f, 0.f, 0.f};
    float mrow[4] = {-1e30f, -1e30f, -1e30f, -1e30f};
    float lrow[4] = {0.f, 0.f, 0.f, 0.f};

    int kend = q0 + 64;
    for (int c0 = 0; c0 < kend; c0 += 64) {
        // ---- QK^T: K frags direct from global (contiguous 16B, L2-hit) ----
        f32x4 sc[4];
#pragma unroll
        for (int n = 0; n < 4; n++) {
            const bf16* kp = kh + (size_t)(c0 + n * 16 + lr) * HDIM + 8 * lg;
            bf16x8 kf0 = *reinterpret_cast<const bf16x8*>(kp);
            bf16x8 kf1 = *reinterpret_cast<const bf16x8*>(kp + 32);
            f32x4 tAcc = f32x4{0.f, 0.f, 0.f, 0.f};
            tAcc = MFMA16(qf0, kf0, tAcc);
            tAcc = MFMA16(qf1, kf1, tAcc);
            sc[n] = tAcc;
        }
        if (c0 == q0) {  // diagonal chunk: causal mask
#pragma unroll
            for (int n = 0; n < 4; n++)
#pragma unroll
                for (int r = 0; r < 4; r++)
                    if (c0 + n * 16 + lr > qrow + 4 * lg + r) sc[n][r] = -1e30f;
        }

        // ---- online softmax (16-lane groups hold a row) ----
        float mnew[4], scl[4], psum[4];
#pragma unroll
        for (int r = 0; r < 4; r++) {
            float mp = fmaxf(fmaxf(sc[0][r], sc[1][r]), fmaxf(sc[2][r], sc[3][r]));
#pragma unroll
            for (int off = 1; off < 16; off <<= 1) mp = fmaxf(mp, __shfl_xor(mp, off));
            mnew[r] = fmaxf(mrow[r], mp);
            scl[r] = __expf(mrow[r] - mnew[r]);
            psum[r] = 0.f;
        }
#pragma unroll
        for (int n = 0; n < 4; n++)
#pragma unroll
            for (int r = 0; r < 4; r++) {
                float p = __expf(sc[n][r] - mnew[r]);
                psum[r] += p;
                plds[wave][4 * lg + r][n * 16 + lr] = (bf16)p;
            }
#pragma unroll
        for (int r = 0; r < 4; r++) {
            float ps = psum[r];
#pragma unroll
            for (int off = 1; off < 16; off <<= 1) ps += __shfl_xor(ps, off);
            lrow[r] = lrow[r] * scl[r] + ps;
            mrow[r] = mnew[r];
        }
#pragma unroll
        for (int n = 0; n < 4; n++) {
            o[n][0] *= scl[0];
            o[n][1] *= scl[1];
            o[n][2] *= scl[2];
            o[n][3] *= scl[3];
        }

        // ---- PV: V^T frags direct from global (contiguous 16B, L2-hit) ----
#pragma unroll
        for (int ks = 0; ks < 2; ks++) {
            bf16x8 pa = *reinterpret_cast<const bf16x8*>(&plds[wave][lr][ks * 32 + 8 * lg]);
#pragma unroll
            for (int n = 0; n < 4; n++) {
                bf16x8 bv = *reinterpret_cast<const bf16x8*>(
                    vh + (size_t)(n * 16 + lr) * SEQ + c0 + ks * 32 + 8 * lg);
                o[n] = MFMA16(pa, bv, o[n]);
            }
        }
    }

    int b_ = bh >> 4, h_ = bh & 15;
#pragma unroll
    for (int r = 0; r < 4; r++) {
        int srow = qrow + 4 * lg + r;
        float inv = 1.f / lrow[r];
        size_t base = ((size_t)b_ * SEQ + srow) * EMB + h_ * HDIM;
#pragma unroll
        for (int n = 0; n < 4; n++) ctx[base + n * 16 + lr] = (bf16)(o[n][r] * inv);
    }
}

// ---------------- launch ---------------------------------------------------
extern "C" void kernel_launch(void* const* d_in, const int* in_sizes, int n_in,
                              void* d_out, int out_size, void* d_ws, size_t ws_size,
                              hipStream_t stream) {
    const float* x  = (const float*)d_in[0];
    const float* Wq = (const float*)d_in[1];
    const float* Wk = (const float*)d_in[2];
    const float* Wv = (const float*)d_in[3];
    const float* Wo = (const float*)d_in[4];
    const float* bo = (const float*)d_in[5];
    const float* W1 = (const float*)d_in[6];
    const float* b1 = (const float*)d_in[7];
    const float* W2 = (const float*)d_in[8];
    const float* b2 = (const float*)d_in[9];
    const float* g1 = (const float*)d_in[10];
    const float* s1 = (const float*)d_in[11];
    const float* g2 = (const float*)d_in[12];
    const float* s2 = (const float*)d_in[13];

    const size_t MB = 1ull << 20;
    char* w = (char*)d_ws;
    bf16* Wqkvt = (bf16*)(w + 0 * MB);            // [3072][1024] contiguous
    bf16* Wqt = Wqkvt;
    bf16* Wkt = (bf16*)(w + 2 * MB);
    bf16* Wvt = (bf16*)(w + 4 * MB);
    bf16* Wot = (bf16*)(w + 6 * MB);
    bf16* W1t = (bf16*)(w + 8 * MB);
    bf16* W2t = (bf16*)(w + 16 * MB);
    bf16* hbuf = (bf16*)(w + 24 * MB);            // h1 / h2 (reused)
    bf16* vtb  = (bf16*)(w + 24 * MB);            // aliases hbuf: used between QKV and LN2
    bf16* qkvb = (bf16*)(w + 32 * MB);            // q @32, k @40, v @48 MB
    bf16* qb   = (bf16*)(w + 32 * MB);
    bf16* kb   = (bf16*)(w + 40 * MB);
    bf16* vb   = (bf16*)(w + 48 * MB);
    bf16* ctxb = (bf16*)(w + 56 * MB);
    bf16* midb = (bf16*)(w + 32 * MB);            // reuses qkv after attn
    float* x1  = (float*)(w + 64 * MB);

    dim3 tb(32, 8);
    // weight transposes (fp32 -> bf16 [N][K]); Wq/Wk/Wv contiguous
    transpose_cast<<<dim3(EMB / 32, EMB / 32), tb, 0, stream>>>(Wq, Wqt, EMB, EMB);
    transpose_cast<<<dim3(EMB / 32, EMB / 32), tb, 0, stream>>>(Wk, Wkt, EMB, EMB);
    transpose_cast<<<dim3(EMB / 32, EMB / 32), tb, 0, stream>>>(Wv, Wvt, EMB, EMB);
    transpose_cast<<<dim3(EMB / 32, EMB / 32), tb, 0, stream>>>(Wo, Wot, EMB, EMB);
    transpose_cast<<<dim3(FFN / 32, EMB / 32), tb, 0, stream>>>(W1, W1t, EMB, FFN);
    transpose_cast<<<dim3(EMB / 32, FFN / 32), tb, 0, stream>>>(W2, W2t, FFN, EMB);

    // LN1
    ln_kernel<<<NTOK, 256, 0, stream>>>(x, g1, s1, hbuf);

    // fused QKV projection: [4096,1024] @ [3072,1024]^T
    gemm_lds<128, 128, 0><<<dim3(NTOK / 128, 3072 / 128), 256, 0, stream>>>(
        hbuf, Wqkvt, NTOK, 3072, EMB, nullptr, qkvb, nullptr, nullptr);

    // V -> V^T  [B,H,64,S]  (hbuf region is free until LN2)
    vtrans<<<dim3(SEQ / 64, BATCH * HEADS), 256, 0, stream>>>(vb, vtb);

    // attention (barrier-free waves, 4 waves/block, XCD-swizzled)
    attn_kernel<<<dim3(SEQ / 64 * BATCH * HEADS), 256, 0, stream>>>(qb, kb, vtb, ctxb);

    // output projection + residual -> x1 (f32)
    gemm_lds<128, 64, 1><<<dim3(NTOK / 128, EMB / 64), 256, 0, stream>>>(
        ctxb, Wot, NTOK, EMB, EMB, x1, nullptr, bo, x);

    // LN2
    ln_kernel<<<NTOK, 256, 0, stream>>>(x1, g2, s2, hbuf);

    // FFN1 + gelu -> bf16 mid
    gemm_lds<128, 128, 2><<<dim3(NTOK / 128, FFN / 128), 256, 0, stream>>>(
        hbuf, W1t, NTOK, FFN, EMB, nullptr, midb, b1, nullptr);

    // FFN2 + bias + residual -> d_out (f32)
    gemm_lds<128, 64, 1><<<dim3(NTOK / 128, EMB / 64), 256, 0, stream>>>(
        midb, W2t, NTOK, EMB, FFN, (float*)d_out, nullptr, b2, x1);
}